// Round 8
// baseline (843.861 us; speedup 1.0000x reference)
//
#include <hip/hip_runtime.h>

#define NN 100000
#define EE 1600000
#define KITER 10

typedef __attribute__((ext_vector_type(8))) short s16x8;
typedef __attribute__((ext_vector_type(4))) float f32x4;

__device__ __forceinline__ short f2bf(float f) {
    union { float f; unsigned u; } v; v.f = f;
    unsigned r = v.u + 0x7FFFu + ((v.u >> 16) & 1u);   // RNE
    return (short)(r >> 16);
}
__device__ __forceinline__ float bf2f(short s) {
    return __uint_as_float((unsigned)(unsigned short)s << 16);
}

__device__ __forceinline__ void gload_lds16(const void* g, void* l) {
    __builtin_amdgcn_global_load_lds(
        (const __attribute__((address_space(1))) void*)g,
        (__attribute__((address_space(3))) void*)l, 16, 0, 0);
}

// ---------------------------------------------------------------------------
// bf16 MFMA GEMM: C = relu(A @ W^T + bias). Tile 128x128, 4 waves, 16x16x32.
// PROVEN round-7 kernel. bf16 output: if CoutHi != nullptr, store split
// lo/hi layout (col<32 -> CoutLo[row*32+col], else CoutHi[row*8+col-32]).
// Optional fp32 copy C2 [row*ldc+col].
// ---------------------------------------------------------------------------
template<int KSTEPS, bool OUT_BF16>
__global__ __launch_bounds__(256)
void mfma_gemm(const short* __restrict__ A, int lda, const short* __restrict__ B,
               const float* __restrict__ bias, int nbias,
               void* __restrict__ Cout, short* __restrict__ CoutHi, int ldc,
               int ncols_store, int nrows, float* __restrict__ C2)
{
    __shared__ short ldsA[128 * 32];
    __shared__ short ldsB[128 * 32];
    const int t    = threadIdx.x;
    const int lane = t & 63;
    const int wid  = t >> 6;
    const int rowBase = blockIdx.y * 128;
    const int colBase = blockIdx.x * 128;
    const int wrow = (wid >> 1) * 64;
    const int wcol = (wid & 1) * 64;

    const int q  = t & 3;    // 8-elem (16B) chunk within 32-wide k tile
    const int rl = t >> 2;   // 0..63

    f32x4 acc[4][4] = {};
    const int KPB = KSTEPS * 32;   // B row stride (padded)

    for (int ks = 0; ks < KSTEPS; ++ks) {
        const int k0 = ks * 32;

        #pragma unroll
        for (int i = 0; i < 2; ++i) {
            const short* srcB = B + (size_t)(colBase + rl + i * 64) * KPB + k0 + q * 8;
            gload_lds16(srcB, &ldsB[wid * 512 + i * 2048]);
        }
        #pragma unroll
        for (int i = 0; i < 2; ++i) {
            int grow = rowBase + rl + i * 64; if (grow > NN - 1) grow = NN - 1;
            const short* srcA = A + (size_t)grow * lda + k0 + q * 8;
            gload_lds16(srcA, &ldsA[wid * 512 + i * 2048]);
        }

        __syncthreads();

        {
            const int kb = lane >> 4;
            const int l16 = lane & 15;
            s16x8 a[4], b[4];
            #pragma unroll
            for (int m = 0; m < 4; ++m)
                a[m] = *(const s16x8*)&ldsA[(wrow + m * 16 + l16) * 32 + kb * 8];
            #pragma unroll
            for (int n = 0; n < 4; ++n)
                b[n] = *(const s16x8*)&ldsB[(wcol + n * 16 + l16) * 32 + kb * 8];
            #pragma unroll
            for (int m = 0; m < 4; ++m)
                #pragma unroll
                for (int n = 0; n < 4; ++n)
                    acc[m][n] = __builtin_amdgcn_mfma_f32_16x16x32_bf16(
                        a[m], b[n], acc[m][n], 0, 0, 0);
        }

        __syncthreads();
    }

    const int crow0 = (lane >> 4) * 4;
    const int ccol  = lane & 15;
    #pragma unroll
    for (int n = 0; n < 4; ++n) {
        int col = colBase + wcol + n * 16 + ccol;
        float bv = (col < nbias) ? bias[col] : 0.f;
        #pragma unroll
        for (int m = 0; m < 4; ++m) {
            #pragma unroll
            for (int j = 0; j < 4; ++j) {
                int row = rowBase + wrow + m * 16 + crow0 + j;
                if (row >= nrows) continue;
                float v = acc[m][n][j] + bv;
                v = fmaxf(v, 0.f);
                if (col < ncols_store) {
                    if (OUT_BF16) {
                        short bvv = f2bf(v);
                        if (CoutHi) {
                            if (col < 32) ((short*)Cout)[(size_t)row * 32 + col] = bvv;
                            else          CoutHi[(size_t)row * 8 + (col - 32)] = bvv;
                        } else {
                            ((short*)Cout)[(size_t)row * ldc + col] = bvv;
                        }
                    } else {
                        ((float*)Cout)[(size_t)row * ldc + col] = v;
                    }
                    if (C2) C2[(size_t)row * ldc + col] = v;
                }
            }
        }
    }
}

// ---------------------------------------------------------------------------
// x fp32 [N][500] -> bf16 [N][500] contiguous, 8 elems/thread
// ---------------------------------------------------------------------------
__global__ void convert_x_kernel(const float* __restrict__ in, short* __restrict__ out) {
    int idx = blockIdx.x * blockDim.x + threadIdx.x;
    if (idx >= (NN * 500) / 8) return;
    const float4* in4 = (const float4*)in;
    float4 a = in4[(size_t)idx * 2];
    float4 b = in4[(size_t)idx * 2 + 1];
    s16x8 s;
    s[0]=f2bf(a.x); s[1]=f2bf(a.y); s[2]=f2bf(a.z); s[3]=f2bf(a.w);
    s[4]=f2bf(b.x); s[5]=f2bf(b.y); s[6]=f2bf(b.z); s[7]=f2bf(b.w);
    *(s16x8*)&out[(size_t)idx * 8] = s;
}

__global__ void convert_w_kernel(const float* __restrict__ in, short* __restrict__ out,
                                 int R, int C, int Rp, int Cp) {
    int idx = blockIdx.x * blockDim.x + threadIdx.x;
    if (idx >= Rp * Cp) return;
    int r = idx / Cp, c = idx - r * Cp;
    float v = (r < R && c < C) ? in[r * C + c] : 0.f;
    out[idx] = f2bf(v);
}

// ---------------------------------------------------------------------------
// Graph build: CSR-by-dst with packed (src, norm) pairs
// ---------------------------------------------------------------------------
__global__ void deg_init_kernel(int* deg, int n) {
    int i = blockIdx.x * blockDim.x + threadIdx.x;
    if (i < n) deg[i] = 1;
}
__global__ void deg_count_kernel(const int* __restrict__ dst, int* deg, int e) {
    int i = blockIdx.x * blockDim.x + threadIdx.x;
    if (i < e) atomicAdd(&deg[dst[i]], 1);
}
__global__ void dinv_kernel(const int* __restrict__ deg, float* __restrict__ dinv,
                            float* __restrict__ dinv2, int n) {
    int i = blockIdx.x * blockDim.x + threadIdx.x;
    if (i < n) {
        float d = (float)deg[i];
        dinv[i] = rsqrtf(d);
        dinv2[i] = 1.0f / d;
    }
}
__global__ __launch_bounds__(256)
void scan1_kernel(const int* __restrict__ deg, int* __restrict__ row_ptr,
                  int* __restrict__ blockSums, int n) {
    __shared__ int sdata[256];
    const int base = blockIdx.x * 2048;
    const int t = threadIdx.x;
    int local[8];
    int s = 0;
    #pragma unroll
    for (int i = 0; i < 8; ++i) {
        int idx = base + t * 8 + i;
        int c = (idx < n) ? (deg[idx] - 1) : 0;
        local[i] = s;
        s += c;
    }
    sdata[t] = s;
    __syncthreads();
    for (int off = 1; off < 256; off <<= 1) {
        int v = (t >= off) ? sdata[t - off] : 0;
        __syncthreads();
        sdata[t] += v;
        __syncthreads();
    }
    int excl = (t == 0) ? 0 : sdata[t - 1];
    #pragma unroll
    for (int i = 0; i < 8; ++i) {
        int idx = base + t * 8 + i;
        if (idx < n) row_ptr[idx] = excl + local[i];
    }
    if (t == 255) blockSums[blockIdx.x] = sdata[255];
}
__global__ void scan2_kernel(int* blockSums, int nb) {
    if (threadIdx.x == 0 && blockIdx.x == 0) {
        int s = 0;
        for (int i = 0; i < nb; ++i) { int v = blockSums[i]; blockSums[i] = s; s += v; }
    }
}
__global__ void scan3_kernel(int* __restrict__ row_ptr, int* __restrict__ cursor,
                             const int* __restrict__ blockSums, int n, int e) {
    int i = blockIdx.x * blockDim.x + threadIdx.x;
    if (i < n) {
        int v = row_ptr[i] + blockSums[i >> 11];
        row_ptr[i] = v;
        cursor[i] = v;
    }
    if (i == 0) row_ptr[n] = e;
}
__global__ void fill_csr_kernel(const int* __restrict__ src, const int* __restrict__ dst,
                                const float* __restrict__ dinv, int* cursor,
                                int2* __restrict__ pairs, int e) {
    int i = blockIdx.x * blockDim.x + threadIdx.x;
    if (i < e) {
        int s = src[i], d = dst[i];
        int pos = atomicAdd(&cursor[d], 1);
        float nv = dinv[s] * dinv[d];
        pairs[pos] = make_int2(s, __float_as_int(nv));
    }
}

// ---------------------------------------------------------------------------
// APPNP step, bf16 split state: h_lo[N][32] bf16 (64B line-aligned rows,
// exactly 1 line per gather) + h_hi[N][8] bf16 (1.6 MB total, L2-resident).
// 5 threads/node: f=0..3 gather lo (16B each), f=4 gathers hi. 64 nodes per
// 320-thread block; fp32 accumulate; x8 unroll (round-5/7 proven pattern).
// ---------------------------------------------------------------------------
__global__ __launch_bounds__(320)
void prop_split_kernel(const short* __restrict__ hin_lo, const short* __restrict__ hin_hi,
                       const float* __restrict__ h0f,
                       const int* __restrict__ rowp, const int2* __restrict__ pairs,
                       const float* __restrict__ dinv2,
                       short* __restrict__ hout_lo, short* __restrict__ hout_hi,
                       float* __restrict__ outF, int n)
{
    const int t = threadIdx.x;
    const int vl = t / 5;
    const int f = t - vl * 5;              // 0..3 -> lo chunk f, 4 -> hi
    const int v = blockIdx.x * 64 + vl;
    if (v >= n) return;

    const bool isLo = (f < 4);
    const short* gbase = isLo ? hin_lo : hin_hi;
    const int gmul = isLo ? 32 : 8;
    const int goff = isLo ? f * 8 : 0;

    float acc[8];
    {
        const float dv = dinv2[v];
        s16x8 s = *(const s16x8*)(gbase + (size_t)v * gmul + goff);
        #pragma unroll
        for (int j = 0; j < 8; ++j) acc[j] = dv * bf2f(s[j]);
    }

    int e = rowp[v];
    const int e1 = rowp[v + 1];

    for (; e + 8 <= e1; e += 8) {
        int2 p0 = pairs[e],     p1 = pairs[e + 1], p2 = pairs[e + 2], p3 = pairs[e + 3];
        int2 p4 = pairs[e + 4], p5 = pairs[e + 5], p6 = pairs[e + 6], p7 = pairs[e + 7];
        s16x8 g0 = *(const s16x8*)(gbase + (size_t)p0.x * gmul + goff);
        s16x8 g1 = *(const s16x8*)(gbase + (size_t)p1.x * gmul + goff);
        s16x8 g2 = *(const s16x8*)(gbase + (size_t)p2.x * gmul + goff);
        s16x8 g3 = *(const s16x8*)(gbase + (size_t)p3.x * gmul + goff);
        s16x8 g4 = *(const s16x8*)(gbase + (size_t)p4.x * gmul + goff);
        s16x8 g5 = *(const s16x8*)(gbase + (size_t)p5.x * gmul + goff);
        s16x8 g6 = *(const s16x8*)(gbase + (size_t)p6.x * gmul + goff);
        s16x8 g7 = *(const s16x8*)(gbase + (size_t)p7.x * gmul + goff);
        float w0 = __int_as_float(p0.y), w1 = __int_as_float(p1.y);
        float w2 = __int_as_float(p2.y), w3 = __int_as_float(p3.y);
        float w4 = __int_as_float(p4.y), w5 = __int_as_float(p5.y);
        float w6 = __int_as_float(p6.y), w7 = __int_as_float(p7.y);
        #pragma unroll
        for (int j = 0; j < 8; ++j) acc[j] = fmaf(w0, bf2f(g0[j]), acc[j]);
        #pragma unroll
        for (int j = 0; j < 8; ++j) acc[j] = fmaf(w1, bf2f(g1[j]), acc[j]);
        #pragma unroll
        for (int j = 0; j < 8; ++j) acc[j] = fmaf(w2, bf2f(g2[j]), acc[j]);
        #pragma unroll
        for (int j = 0; j < 8; ++j) acc[j] = fmaf(w3, bf2f(g3[j]), acc[j]);
        #pragma unroll
        for (int j = 0; j < 8; ++j) acc[j] = fmaf(w4, bf2f(g4[j]), acc[j]);
        #pragma unroll
        for (int j = 0; j < 8; ++j) acc[j] = fmaf(w5, bf2f(g5[j]), acc[j]);
        #pragma unroll
        for (int j = 0; j < 8; ++j) acc[j] = fmaf(w6, bf2f(g6[j]), acc[j]);
        #pragma unroll
        for (int j = 0; j < 8; ++j) acc[j] = fmaf(w7, bf2f(g7[j]), acc[j]);
    }
    for (; e < e1; ++e) {
        int2 p = pairs[e];
        s16x8 g = *(const s16x8*)(gbase + (size_t)p.x * gmul + goff);
        float w = __int_as_float(p.y);
        #pragma unroll
        for (int j = 0; j < 8; ++j) acc[j] = fmaf(w, bf2f(g[j]), acc[j]);
    }

    const float* h0p = h0f + (size_t)v * 40 + (isLo ? f * 8 : 32);
    float o[8];
    #pragma unroll
    for (int j = 0; j < 8; ++j) o[j] = fmaf(0.9f, acc[j], 0.1f * h0p[j]);

    if (outF) {
        float4* op = (float4*)(outF + (size_t)v * 40 + (isLo ? f * 8 : 32));
        op[0] = make_float4(o[0], o[1], o[2], o[3]);
        op[1] = make_float4(o[4], o[5], o[6], o[7]);
    } else {
        s16x8 s;
        #pragma unroll
        for (int j = 0; j < 8; ++j) s[j] = f2bf(o[j]);
        short* obase = isLo ? hout_lo : hout_hi;
        *(s16x8*)(obase + (size_t)v * gmul + goff) = s;
    }
}

// ---------------------------------------------------------------------------
extern "C" void kernel_launch(void* const* d_in, const int* in_sizes, int n_in,
                              void* d_out, int out_size, void* d_ws, size_t ws_size,
                              hipStream_t stream) {
    const float* x  = (const float*)d_in[0];
    const int* ei   = (const int*)d_in[1];
    const float* W0 = (const float*)d_in[2];
    const float* b0 = (const float*)d_in[3];
    const float* W1 = (const float*)d_in[4];
    const float* b1 = (const float*)d_in[5];
    const float* W2 = (const float*)d_in[6];
    const float* b2 = (const float*)d_in[7];
    float* out = (float*)d_out;
    char* ws = (char*)d_ws;

    const int* src = ei;
    const int* dst = ei + EE;

    // ---- Workspace layout (round-7 proven scheme), total 151.6 MB ----
    // Phase 1 (MLP): xb [0,100e6) ; h1b [100e6,151.2e6) ; weights at 151.2e6
    // Phase 2 (after GEMM0, region 0 reused): h2b, h0lo/hi, h0f, hA*, hB*
    // Phase 3 (after GEMM1, region 100e6 reused): pairs + graph arrays
    short* xb   = (short*)(ws);                   // [N][500] bf16
    short* h1b  = (short*)(ws + 100000000);       // [N][256] bf16
    short* W0b  = (short*)(ws + 151200000);       // [256][512]
    short* W1b  = (short*)(ws + 151462144);       // [128][256]
    short* W2b  = (short*)(ws + 151527680);       // [128][128] (ends 151,560,448)

    short* h2b  = (short*)(ws);                   // [N][128] bf16 (reuse xb)
    short* h0lo = (short*)(ws + 25600000);        // [N][32] bf16 -> 32.0e6
    short* h0hi = (short*)(ws + 32000000);        // [N][8]  bf16 -> 33.6e6
    float* h0f  = (float*)(ws + 33600000);        // [N][40] f32  -> 49.6e6
    short* hAlo = (short*)(ws + 49600000);        // [N][32] -> 56.0e6
    short* hAhi = (short*)(ws + 56000000);        // [N][8]  -> 57.6e6
    short* hBlo = (short*)(ws + 57600000);        // [N][32] -> 64.0e6
    short* hBhi = (short*)(ws + 64000000);        // [N][8]  -> 65.6e6

    int2*  pairs= (int2*) (ws + 100000000);       // [E] (reuse h1b)
    int*   deg  = (int*)  (ws + 112800000);       // [N]
    float* dinv = (float*)(ws + 113200000);       // [N]
    float* dnv2 = (float*)(ws + 113600000);       // [N]
    int*   rowp = (int*)  (ws + 114000000);       // [N+1]
    int*   curs = (int*)  (ws + 114400008);       // [N]
    int*   bsum = (int*)  (ws + 114800008);       // [4096]
    (void)ws_size; (void)in_sizes; (void)n_in; (void)out_size;

    // ---- conversions ----
    convert_x_kernel<<<((NN * 500 / 8) + 255) / 256, 256, 0, stream>>>(x, xb);
    convert_w_kernel<<<(256 * 512 + 255) / 256, 256, 0, stream>>>(W0, W0b, 256, 500, 256, 512);
    convert_w_kernel<<<(128 * 256 + 255) / 256, 256, 0, stream>>>(W1, W1b, 128, 256, 128, 256);
    convert_w_kernel<<<(128 * 128 + 255) / 256, 256, 0, stream>>>(W2, W2b, 40, 128, 128, 128);

    // ---- MLP encoder ----
    const int NBLK = (NN + 127) / 128;  // 782
    mfma_gemm<16, true ><<<dim3(2, NBLK), 256, 0, stream>>>(
        xb, 500, W0b, b0, 256, (void*)h1b, nullptr, 256, 256, NN, nullptr);
    mfma_gemm<8,  true ><<<dim3(1, NBLK), 256, 0, stream>>>(
        h1b, 256, W1b, b1, 128, (void*)h2b, nullptr, 128, 128, NN, nullptr);
    mfma_gemm<4,  true ><<<dim3(1, NBLK), 256, 0, stream>>>(
        h2b, 128, W2b, b2, 40, (void*)h0lo, h0hi, 40, 40, NN, h0f);  // split + fp32

    // ---- graph build (after GEMM1: h1b region is dead) ----
    {
        int nb_n = (NN + 255) / 256;
        int nb_e = (EE + 255) / 256;
        deg_init_kernel<<<nb_n, 256, 0, stream>>>(deg, NN);
        deg_count_kernel<<<nb_e, 256, 0, stream>>>(dst, deg, EE);
        dinv_kernel<<<nb_n, 256, 0, stream>>>(deg, dinv, dnv2, NN);
        int nb_scan = (NN + 2047) / 2048;
        scan1_kernel<<<nb_scan, 256, 0, stream>>>(deg, rowp, bsum, NN);
        scan2_kernel<<<1, 64, 0, stream>>>(bsum, nb_scan);
        scan3_kernel<<<nb_n, 256, 0, stream>>>(rowp, curs, bsum, NN, EE);
        fill_csr_kernel<<<nb_e, 256, 0, stream>>>(src, dst, dinv, curs, pairs, EE);
    }

    // ---- APPNP propagation (bf16 split state) ----
    {
        dim3 blk(320);
        dim3 grd((NN + 63) / 64);  // 1563
        const short* hlo = h0lo;
        const short* hhi = h0hi;
        for (int it = 0; it < KITER; ++it) {
            short* olo = (it & 1) ? hBlo : hAlo;
            short* ohi = (it & 1) ? hBhi : hAhi;
            float* fin = (it == KITER - 1) ? out : nullptr;
            prop_split_kernel<<<grd, blk, 0, stream>>>(
                hlo, hhi, h0f, rowp, pairs, dnv2, olo, ohi, fin, NN);
            hlo = olo; hhi = ohi;
        }
    }
}

// Round 9
// 837.342 us; speedup vs baseline: 1.0078x; 1.0078x over previous
//
#include <hip/hip_runtime.h>

#define NN 100000
#define EE 1600000
#define KITER 10

typedef __attribute__((ext_vector_type(8))) short s16x8;
typedef __attribute__((ext_vector_type(4))) float f32x4;
typedef __attribute__((ext_vector_type(2))) int i32x2;

__device__ __forceinline__ short f2bf(float f) {
    union { float f; unsigned u; } v; v.f = f;
    unsigned r = v.u + 0x7FFFu + ((v.u >> 16) & 1u);   // RNE
    return (short)(r >> 16);
}
__device__ __forceinline__ float bf2f(short s) {
    return __uint_as_float((unsigned)(unsigned short)s << 16);
}

__device__ __forceinline__ void gload_lds16(const void* g, void* l) {
    __builtin_amdgcn_global_load_lds(
        (const __attribute__((address_space(1))) void*)g,
        (__attribute__((address_space(3))) void*)l, 16, 0, 0);
}

// ---------------------------------------------------------------------------
// bf16 MFMA GEMM: C = relu(A @ W^T + bias). Tile 128x128, 4 waves, 16x16x32.
// PROVEN round-7 kernel, unchanged.
// ---------------------------------------------------------------------------
template<int KSTEPS, bool OUT_BF16>
__global__ __launch_bounds__(256)
void mfma_gemm(const short* __restrict__ A, int lda, const short* __restrict__ B,
               const float* __restrict__ bias, int nbias,
               void* __restrict__ Cout, int ldc, int ncols_store, int nrows,
               float* __restrict__ C2)
{
    __shared__ short ldsA[128 * 32];
    __shared__ short ldsB[128 * 32];
    const int t    = threadIdx.x;
    const int lane = t & 63;
    const int wid  = t >> 6;
    const int rowBase = blockIdx.y * 128;
    const int colBase = blockIdx.x * 128;
    const int wrow = (wid >> 1) * 64;
    const int wcol = (wid & 1) * 64;

    const int q  = t & 3;    // 8-elem (16B) chunk within 32-wide k tile
    const int rl = t >> 2;   // 0..63

    f32x4 acc[4][4] = {};
    const int KPB = KSTEPS * 32;   // B row stride (padded)

    for (int ks = 0; ks < KSTEPS; ++ks) {
        const int k0 = ks * 32;

        #pragma unroll
        for (int i = 0; i < 2; ++i) {
            const short* srcB = B + (size_t)(colBase + rl + i * 64) * KPB + k0 + q * 8;
            gload_lds16(srcB, &ldsB[wid * 512 + i * 2048]);
        }
        #pragma unroll
        for (int i = 0; i < 2; ++i) {
            int grow = rowBase + rl + i * 64; if (grow > NN - 1) grow = NN - 1;
            const short* srcA = A + (size_t)grow * lda + k0 + q * 8;
            gload_lds16(srcA, &ldsA[wid * 512 + i * 2048]);
        }

        __syncthreads();

        {
            const int kb = lane >> 4;
            const int l16 = lane & 15;
            s16x8 a[4], b[4];
            #pragma unroll
            for (int m = 0; m < 4; ++m)
                a[m] = *(const s16x8*)&ldsA[(wrow + m * 16 + l16) * 32 + kb * 8];
            #pragma unroll
            for (int n = 0; n < 4; ++n)
                b[n] = *(const s16x8*)&ldsB[(wcol + n * 16 + l16) * 32 + kb * 8];
            #pragma unroll
            for (int m = 0; m < 4; ++m)
                #pragma unroll
                for (int n = 0; n < 4; ++n)
                    acc[m][n] = __builtin_amdgcn_mfma_f32_16x16x32_bf16(
                        a[m], b[n], acc[m][n], 0, 0, 0);
        }

        __syncthreads();
    }

    const int crow0 = (lane >> 4) * 4;
    const int ccol  = lane & 15;
    #pragma unroll
    for (int n = 0; n < 4; ++n) {
        int col = colBase + wcol + n * 16 + ccol;
        float bv = (col < nbias) ? bias[col] : 0.f;
        #pragma unroll
        for (int m = 0; m < 4; ++m) {
            #pragma unroll
            for (int j = 0; j < 4; ++j) {
                int row = rowBase + wrow + m * 16 + crow0 + j;
                if (row >= nrows) continue;
                float v = acc[m][n][j] + bv;
                v = fmaxf(v, 0.f);
                if (col < ncols_store) {
                    if (OUT_BF16)
                        ((short*)Cout)[(size_t)row * ldc + col] = f2bf(v);
                    else
                        ((float*)Cout)[(size_t)row * ldc + col] = v;
                    if (C2) C2[(size_t)row * ldc + col] = v;
                }
            }
        }
    }
}

// ---------------------------------------------------------------------------
// x fp32 [N][500] -> bf16 [N][500] contiguous, 8 elems/thread
// ---------------------------------------------------------------------------
__global__ void convert_x_kernel(const float* __restrict__ in, short* __restrict__ out) {
    int idx = blockIdx.x * blockDim.x + threadIdx.x;
    if (idx >= (NN * 500) / 8) return;
    const float4* in4 = (const float4*)in;
    float4 a = in4[(size_t)idx * 2];
    float4 b = in4[(size_t)idx * 2 + 1];
    s16x8 s;
    s[0]=f2bf(a.x); s[1]=f2bf(a.y); s[2]=f2bf(a.z); s[3]=f2bf(a.w);
    s[4]=f2bf(b.x); s[5]=f2bf(b.y); s[6]=f2bf(b.z); s[7]=f2bf(b.w);
    *(s16x8*)&out[(size_t)idx * 8] = s;
}

__global__ void convert_w_kernel(const float* __restrict__ in, short* __restrict__ out,
                                 int R, int C, int Rp, int Cp) {
    int idx = blockIdx.x * blockDim.x + threadIdx.x;
    if (idx >= Rp * Cp) return;
    int r = idx / Cp, c = idx - r * Cp;
    float v = (r < R && c < C) ? in[r * C + c] : 0.f;
    out[idx] = f2bf(v);
}

// ---------------------------------------------------------------------------
// Graph build: CSR-by-dst with packed (src, norm) pairs
// ---------------------------------------------------------------------------
__global__ void deg_init_kernel(int* deg, int n) {
    int i = blockIdx.x * blockDim.x + threadIdx.x;
    if (i < n) deg[i] = 1;
}
__global__ void deg_count_kernel(const int* __restrict__ dst, int* deg, int e) {
    int i = blockIdx.x * blockDim.x + threadIdx.x;
    if (i < e) atomicAdd(&deg[dst[i]], 1);
}
__global__ void dinv_kernel(const int* __restrict__ deg, float* __restrict__ dinv,
                            float* __restrict__ dinv2, int n) {
    int i = blockIdx.x * blockDim.x + threadIdx.x;
    if (i < n) {
        float d = (float)deg[i];
        dinv[i] = rsqrtf(d);
        dinv2[i] = 1.0f / d;
    }
}
__global__ __launch_bounds__(256)
void scan1_kernel(const int* __restrict__ deg, int* __restrict__ row_ptr,
                  int* __restrict__ blockSums, int n) {
    __shared__ int sdata[256];
    const int base = blockIdx.x * 2048;
    const int t = threadIdx.x;
    int local[8];
    int s = 0;
    #pragma unroll
    for (int i = 0; i < 8; ++i) {
        int idx = base + t * 8 + i;
        int c = (idx < n) ? (deg[idx] - 1) : 0;
        local[i] = s;
        s += c;
    }
    sdata[t] = s;
    __syncthreads();
    for (int off = 1; off < 256; off <<= 1) {
        int v = (t >= off) ? sdata[t - off] : 0;
        __syncthreads();
        sdata[t] += v;
        __syncthreads();
    }
    int excl = (t == 0) ? 0 : sdata[t - 1];
    #pragma unroll
    for (int i = 0; i < 8; ++i) {
        int idx = base + t * 8 + i;
        if (idx < n) row_ptr[idx] = excl + local[i];
    }
    if (t == 255) blockSums[blockIdx.x] = sdata[255];
}
__global__ void scan2_kernel(int* blockSums, int nb) {
    if (threadIdx.x == 0 && blockIdx.x == 0) {
        int s = 0;
        for (int i = 0; i < nb; ++i) { int v = blockSums[i]; blockSums[i] = s; s += v; }
    }
}
__global__ void scan3_kernel(int* __restrict__ row_ptr, int* __restrict__ cursor,
                             const int* __restrict__ blockSums, int n, int e) {
    int i = blockIdx.x * blockDim.x + threadIdx.x;
    if (i < n) {
        int v = row_ptr[i] + blockSums[i >> 11];
        row_ptr[i] = v;
        cursor[i] = v;
    }
    if (i == 0) row_ptr[n] = e;
}
__global__ void fill_csr_kernel(const int* __restrict__ src, const int* __restrict__ dst,
                                const float* __restrict__ dinv, int* cursor,
                                int2* __restrict__ pairs, int e) {
    int i = blockIdx.x * blockDim.x + threadIdx.x;
    if (i < e) {
        int s = src[i], d = dst[i];
        int pos = atomicAdd(&cursor[d], 1);
        float nv = dinv[s] * dinv[d];
        pairs[pos] = make_int2(s, __float_as_int(nv));
    }
}

// ---------------------------------------------------------------------------
// APPNP step, bf16 state (round-7 proven structure). ONLY change vs round 7:
// all STREAMING accesses (pairs, h0f teleport read, output stores) use
// non-temporal hints so the per-XCD L2 retains the randomly-gathered h table.
// ---------------------------------------------------------------------------
__global__ __launch_bounds__(320)
void prop_bf16_kernel(const short* __restrict__ hin, const float* __restrict__ h0f,
                      const int* __restrict__ rowp, const int2* __restrict__ pairs,
                      const float* __restrict__ dinv2,
                      short* __restrict__ hout, float* __restrict__ outF, int n)
{
    const int t = threadIdx.x;
    const int vl = t / 5;
    const int f = t - vl * 5;              // 0..4 -> features [f*8, f*8+8)
    const int v = blockIdx.x * 64 + vl;
    if (v >= n) return;

    float acc[8];
    {
        const float dv = dinv2[v];
        s16x8 s = *(const s16x8*)(hin + (size_t)v * 40 + f * 8);
        #pragma unroll
        for (int j = 0; j < 8; ++j) acc[j] = dv * bf2f(s[j]);
    }

    int e = rowp[v];
    const int e1 = rowp[v + 1];
    const i32x2* pr = (const i32x2*)pairs;

    for (; e + 8 <= e1; e += 8) {
        i32x2 p0 = __builtin_nontemporal_load(pr + e);
        i32x2 p1 = __builtin_nontemporal_load(pr + e + 1);
        i32x2 p2 = __builtin_nontemporal_load(pr + e + 2);
        i32x2 p3 = __builtin_nontemporal_load(pr + e + 3);
        i32x2 p4 = __builtin_nontemporal_load(pr + e + 4);
        i32x2 p5 = __builtin_nontemporal_load(pr + e + 5);
        i32x2 p6 = __builtin_nontemporal_load(pr + e + 6);
        i32x2 p7 = __builtin_nontemporal_load(pr + e + 7);
        s16x8 g0 = *(const s16x8*)(hin + (size_t)p0[0] * 40 + f * 8);
        s16x8 g1 = *(const s16x8*)(hin + (size_t)p1[0] * 40 + f * 8);
        s16x8 g2 = *(const s16x8*)(hin + (size_t)p2[0] * 40 + f * 8);
        s16x8 g3 = *(const s16x8*)(hin + (size_t)p3[0] * 40 + f * 8);
        s16x8 g4 = *(const s16x8*)(hin + (size_t)p4[0] * 40 + f * 8);
        s16x8 g5 = *(const s16x8*)(hin + (size_t)p5[0] * 40 + f * 8);
        s16x8 g6 = *(const s16x8*)(hin + (size_t)p6[0] * 40 + f * 8);
        s16x8 g7 = *(const s16x8*)(hin + (size_t)p7[0] * 40 + f * 8);
        float w0 = __int_as_float(p0[1]), w1 = __int_as_float(p1[1]);
        float w2 = __int_as_float(p2[1]), w3 = __int_as_float(p3[1]);
        float w4 = __int_as_float(p4[1]), w5 = __int_as_float(p5[1]);
        float w6 = __int_as_float(p6[1]), w7 = __int_as_float(p7[1]);
        #pragma unroll
        for (int j = 0; j < 8; ++j) acc[j] = fmaf(w0, bf2f(g0[j]), acc[j]);
        #pragma unroll
        for (int j = 0; j < 8; ++j) acc[j] = fmaf(w1, bf2f(g1[j]), acc[j]);
        #pragma unroll
        for (int j = 0; j < 8; ++j) acc[j] = fmaf(w2, bf2f(g2[j]), acc[j]);
        #pragma unroll
        for (int j = 0; j < 8; ++j) acc[j] = fmaf(w3, bf2f(g3[j]), acc[j]);
        #pragma unroll
        for (int j = 0; j < 8; ++j) acc[j] = fmaf(w4, bf2f(g4[j]), acc[j]);
        #pragma unroll
        for (int j = 0; j < 8; ++j) acc[j] = fmaf(w5, bf2f(g5[j]), acc[j]);
        #pragma unroll
        for (int j = 0; j < 8; ++j) acc[j] = fmaf(w6, bf2f(g6[j]), acc[j]);
        #pragma unroll
        for (int j = 0; j < 8; ++j) acc[j] = fmaf(w7, bf2f(g7[j]), acc[j]);
    }
    for (; e < e1; ++e) {
        i32x2 p = __builtin_nontemporal_load(pr + e);
        s16x8 g = *(const s16x8*)(hin + (size_t)p[0] * 40 + f * 8);
        float w = __int_as_float(p[1]);
        #pragma unroll
        for (int j = 0; j < 8; ++j) acc[j] = fmaf(w, bf2f(g[j]), acc[j]);
    }

    const f32x4* h0p = (const f32x4*)(h0f + (size_t)v * 40 + f * 8);
    f32x4 h0a = __builtin_nontemporal_load(h0p);
    f32x4 h0b = __builtin_nontemporal_load(h0p + 1);
    float o[8];
    #pragma unroll
    for (int j = 0; j < 4; ++j) o[j] = fmaf(0.9f, acc[j], 0.1f * h0a[j]);
    #pragma unroll
    for (int j = 0; j < 4; ++j) o[4 + j] = fmaf(0.9f, acc[4 + j], 0.1f * h0b[j]);

    if (outF) {
        f32x4* op = (f32x4*)(outF + (size_t)v * 40 + f * 8);
        f32x4 o0 = {o[0], o[1], o[2], o[3]};
        f32x4 o1 = {o[4], o[5], o[6], o[7]};
        __builtin_nontemporal_store(o0, op);
        __builtin_nontemporal_store(o1, op + 1);
    } else {
        s16x8 s;
        #pragma unroll
        for (int j = 0; j < 8; ++j) s[j] = f2bf(o[j]);
        __builtin_nontemporal_store(s, (s16x8*)(hout + (size_t)v * 40 + f * 8));
    }
}

// ---------------------------------------------------------------------------
extern "C" void kernel_launch(void* const* d_in, const int* in_sizes, int n_in,
                              void* d_out, int out_size, void* d_ws, size_t ws_size,
                              hipStream_t stream) {
    const float* x  = (const float*)d_in[0];
    const int* ei   = (const int*)d_in[1];
    const float* W0 = (const float*)d_in[2];
    const float* b0 = (const float*)d_in[3];
    const float* W1 = (const float*)d_in[4];
    const float* b1 = (const float*)d_in[5];
    const float* W2 = (const float*)d_in[6];
    const float* b2 = (const float*)d_in[7];
    float* out = (float*)d_out;
    char* ws = (char*)d_ws;

    const int* src = ei;
    const int* dst = ei + EE;

    // ---- Workspace layout (round-7 proven), total 151.6 MB ----
    short* xb   = (short*)(ws);                   // [N][500] bf16
    short* h1b  = (short*)(ws + 100000000);       // [N][256] bf16
    short* W0b  = (short*)(ws + 151200000);       // [256][512]
    short* W1b  = (short*)(ws + 151462144);       // [128][256]
    short* W2b  = (short*)(ws + 151527680);       // [128][128] (ends 151,560,448)

    short* h2b  = (short*)(ws);                   // [N][128] bf16 (reuse xb)
    short* h0b  = (short*)(ws + 25600000);        // [N][40] bf16  ->  33.6e6
    float* h0f  = (float*)(ws + 33600000);        // [N][40] f32   ->  49.6e6
    short* hA   = (short*)(ws + 49600000);        // [N][40] bf16  ->  57.6e6
    short* hB   = (short*)(ws + 57600000);        // [N][40] bf16  ->  65.6e6

    int2*  pairs= (int2*) (ws + 100000000);       // [E] (reuse h1b)
    int*   deg  = (int*)  (ws + 112800000);       // [N]
    float* dinv = (float*)(ws + 113200000);       // [N]
    float* dnv2 = (float*)(ws + 113600000);       // [N]
    int*   rowp = (int*)  (ws + 114000000);       // [N+1]
    int*   curs = (int*)  (ws + 114400008);       // [N]
    int*   bsum = (int*)  (ws + 114800008);       // [4096]
    (void)ws_size; (void)in_sizes; (void)n_in; (void)out_size;

    // ---- conversions ----
    convert_x_kernel<<<((NN * 500 / 8) + 255) / 256, 256, 0, stream>>>(x, xb);
    convert_w_kernel<<<(256 * 512 + 255) / 256, 256, 0, stream>>>(W0, W0b, 256, 500, 256, 512);
    convert_w_kernel<<<(128 * 256 + 255) / 256, 256, 0, stream>>>(W1, W1b, 128, 256, 128, 256);
    convert_w_kernel<<<(128 * 128 + 255) / 256, 256, 0, stream>>>(W2, W2b, 40, 128, 128, 128);

    // ---- MLP encoder ----
    const int NBLK = (NN + 127) / 128;  // 782
    mfma_gemm<16, true ><<<dim3(2, NBLK), 256, 0, stream>>>(
        xb, 500, W0b, b0, 256, (void*)h1b, 256, 256, NN, nullptr);
    mfma_gemm<8,  true ><<<dim3(1, NBLK), 256, 0, stream>>>(
        h1b, 256, W1b, b1, 128, (void*)h2b, 128, 128, NN, nullptr);
    mfma_gemm<4,  true ><<<dim3(1, NBLK), 256, 0, stream>>>(
        h2b, 128, W2b, b2, 40, (void*)h0b, 40, 40, NN, h0f);  // bf16 + fp32 h0

    // ---- graph build (after GEMM1: h1b region is dead) ----
    {
        int nb_n = (NN + 255) / 256;
        int nb_e = (EE + 255) / 256;
        deg_init_kernel<<<nb_n, 256, 0, stream>>>(deg, NN);
        deg_count_kernel<<<nb_e, 256, 0, stream>>>(dst, deg, EE);
        dinv_kernel<<<nb_n, 256, 0, stream>>>(deg, dinv, dnv2, NN);
        int nb_scan = (NN + 2047) / 2048;
        scan1_kernel<<<nb_scan, 256, 0, stream>>>(deg, rowp, bsum, NN);
        scan2_kernel<<<1, 64, 0, stream>>>(bsum, nb_scan);
        scan3_kernel<<<nb_n, 256, 0, stream>>>(rowp, curs, bsum, NN, EE);
        fill_csr_kernel<<<nb_e, 256, 0, stream>>>(src, dst, dinv, curs, pairs, EE);
    }

    // ---- APPNP propagation (bf16 state, nt-hinted streams) ----
    {
        dim3 blk(320);
        dim3 grd((NN + 63) / 64);  // 1563
        const short* hin = h0b;
        for (int it = 0; it < KITER; ++it) {
            short* hout = (it & 1) ? hB : hA;
            float* fin  = (it == KITER - 1) ? out : nullptr;
            prop_bf16_kernel<<<grd, blk, 0, stream>>>(
                hin, h0f, rowp, pairs, dnv2, hout, fin, NN);
            hin = hout;
        }
    }
}

// Round 10
// 823.717 us; speedup vs baseline: 1.0245x; 1.0165x over previous
//
#include <hip/hip_runtime.h>

#define NN 100000
#define EE 1600000
#define KITER 10

typedef __attribute__((ext_vector_type(8))) short s16x8;
typedef __attribute__((ext_vector_type(4))) float f32x4;

__device__ __forceinline__ short f2bf(float f) {
    union { float f; unsigned u; } v; v.f = f;
    unsigned r = v.u + 0x7FFFu + ((v.u >> 16) & 1u);   // RNE
    return (short)(r >> 16);
}
__device__ __forceinline__ float bf2f(short s) {
    return __uint_as_float((unsigned)(unsigned short)s << 16);
}

__device__ __forceinline__ void gload_lds16(const void* g, void* l) {
    __builtin_amdgcn_global_load_lds(
        (const __attribute__((address_space(1))) void*)g,
        (__attribute__((address_space(3))) void*)l, 16, 0, 0);
}

// ---------------------------------------------------------------------------
// bf16 MFMA GEMM: C = relu(A @ W^T + bias). Tile 128x128, 4 waves, 16x16x32.
// PROVEN round-8 version (passed, absmax 0.0078125): bf16 output optionally
// split lo/hi (col<32 -> Cout[row*32+col], else CoutHi[row*8+col-32]);
// optional fp32 copy C2[row*ldc+col].
// ---------------------------------------------------------------------------
template<int KSTEPS, bool OUT_BF16>
__global__ __launch_bounds__(256)
void mfma_gemm(const short* __restrict__ A, int lda, const short* __restrict__ B,
               const float* __restrict__ bias, int nbias,
               void* __restrict__ Cout, short* __restrict__ CoutHi, int ldc,
               int ncols_store, int nrows, float* __restrict__ C2)
{
    __shared__ short ldsA[128 * 32];
    __shared__ short ldsB[128 * 32];
    const int t    = threadIdx.x;
    const int lane = t & 63;
    const int wid  = t >> 6;
    const int rowBase = blockIdx.y * 128;
    const int colBase = blockIdx.x * 128;
    const int wrow = (wid >> 1) * 64;
    const int wcol = (wid & 1) * 64;

    const int q  = t & 3;    // 8-elem (16B) chunk within 32-wide k tile
    const int rl = t >> 2;   // 0..63

    f32x4 acc[4][4] = {};
    const int KPB = KSTEPS * 32;   // B row stride (padded)

    for (int ks = 0; ks < KSTEPS; ++ks) {
        const int k0 = ks * 32;

        #pragma unroll
        for (int i = 0; i < 2; ++i) {
            const short* srcB = B + (size_t)(colBase + rl + i * 64) * KPB + k0 + q * 8;
            gload_lds16(srcB, &ldsB[wid * 512 + i * 2048]);
        }
        #pragma unroll
        for (int i = 0; i < 2; ++i) {
            int grow = rowBase + rl + i * 64; if (grow > NN - 1) grow = NN - 1;
            const short* srcA = A + (size_t)grow * lda + k0 + q * 8;
            gload_lds16(srcA, &ldsA[wid * 512 + i * 2048]);
        }

        __syncthreads();

        {
            const int kb = lane >> 4;
            const int l16 = lane & 15;
            s16x8 a[4], b[4];
            #pragma unroll
            for (int m = 0; m < 4; ++m)
                a[m] = *(const s16x8*)&ldsA[(wrow + m * 16 + l16) * 32 + kb * 8];
            #pragma unroll
            for (int n = 0; n < 4; ++n)
                b[n] = *(const s16x8*)&ldsB[(wcol + n * 16 + l16) * 32 + kb * 8];
            #pragma unroll
            for (int m = 0; m < 4; ++m)
                #pragma unroll
                for (int n = 0; n < 4; ++n)
                    acc[m][n] = __builtin_amdgcn_mfma_f32_16x16x32_bf16(
                        a[m], b[n], acc[m][n], 0, 0, 0);
        }

        __syncthreads();
    }

    const int crow0 = (lane >> 4) * 4;
    const int ccol  = lane & 15;
    #pragma unroll
    for (int n = 0; n < 4; ++n) {
        int col = colBase + wcol + n * 16 + ccol;
        float bv = (col < nbias) ? bias[col] : 0.f;
        #pragma unroll
        for (int m = 0; m < 4; ++m) {
            #pragma unroll
            for (int j = 0; j < 4; ++j) {
                int row = rowBase + wrow + m * 16 + crow0 + j;
                if (row >= nrows) continue;
                float v = acc[m][n][j] + bv;
                v = fmaxf(v, 0.f);
                if (col < ncols_store) {
                    if (OUT_BF16) {
                        short bvv = f2bf(v);
                        if (CoutHi) {
                            if (col < 32) ((short*)Cout)[(size_t)row * 32 + col] = bvv;
                            else          CoutHi[(size_t)row * 8 + (col - 32)] = bvv;
                        } else {
                            ((short*)Cout)[(size_t)row * ldc + col] = bvv;
                        }
                    } else {
                        ((float*)Cout)[(size_t)row * ldc + col] = v;
                    }
                    if (C2) C2[(size_t)row * ldc + col] = v;
                }
            }
        }
    }
}

// ---------------------------------------------------------------------------
// x fp32 [N][500] -> bf16 [N][500] contiguous, 8 elems/thread
// ---------------------------------------------------------------------------
__global__ void convert_x_kernel(const float* __restrict__ in, short* __restrict__ out) {
    int idx = blockIdx.x * blockDim.x + threadIdx.x;
    if (idx >= (NN * 500) / 8) return;
    const float4* in4 = (const float4*)in;
    float4 a = in4[(size_t)idx * 2];
    float4 b = in4[(size_t)idx * 2 + 1];
    s16x8 s;
    s[0]=f2bf(a.x); s[1]=f2bf(a.y); s[2]=f2bf(a.z); s[3]=f2bf(a.w);
    s[4]=f2bf(b.x); s[5]=f2bf(b.y); s[6]=f2bf(b.z); s[7]=f2bf(b.w);
    *(s16x8*)&out[(size_t)idx * 8] = s;
}

__global__ void convert_w_kernel(const float* __restrict__ in, short* __restrict__ out,
                                 int R, int C, int Rp, int Cp) {
    int idx = blockIdx.x * blockDim.x + threadIdx.x;
    if (idx >= Rp * Cp) return;
    int r = idx / Cp, c = idx - r * Cp;
    float v = (r < R && c < C) ? in[r * C + c] : 0.f;
    out[idx] = f2bf(v);
}

// ---------------------------------------------------------------------------
// Graph build: CSR-by-dst with packed (src, norm) pairs
// ---------------------------------------------------------------------------
__global__ void deg_init_kernel(int* deg, int n) {
    int i = blockIdx.x * blockDim.x + threadIdx.x;
    if (i < n) deg[i] = 1;
}
__global__ void deg_count_kernel(const int* __restrict__ dst, int* deg, int e) {
    int i = blockIdx.x * blockDim.x + threadIdx.x;
    if (i < e) atomicAdd(&deg[dst[i]], 1);
}
__global__ void dinv_kernel(const int* __restrict__ deg, float* __restrict__ dinv,
                            float* __restrict__ dinv2, int n) {
    int i = blockIdx.x * blockDim.x + threadIdx.x;
    if (i < n) {
        float d = (float)deg[i];
        dinv[i] = rsqrtf(d);
        dinv2[i] = 1.0f / d;
    }
}
__global__ __launch_bounds__(256)
void scan1_kernel(const int* __restrict__ deg, int* __restrict__ row_ptr,
                  int* __restrict__ blockSums, int n) {
    __shared__ int sdata[256];
    const int base = blockIdx.x * 2048;
    const int t = threadIdx.x;
    int local[8];
    int s = 0;
    #pragma unroll
    for (int i = 0; i < 8; ++i) {
        int idx = base + t * 8 + i;
        int c = (idx < n) ? (deg[idx] - 1) : 0;
        local[i] = s;
        s += c;
    }
    sdata[t] = s;
    __syncthreads();
    for (int off = 1; off < 256; off <<= 1) {
        int v = (t >= off) ? sdata[t - off] : 0;
        __syncthreads();
        sdata[t] += v;
        __syncthreads();
    }
    int excl = (t == 0) ? 0 : sdata[t - 1];
    #pragma unroll
    for (int i = 0; i < 8; ++i) {
        int idx = base + t * 8 + i;
        if (idx < n) row_ptr[idx] = excl + local[i];
    }
    if (t == 255) blockSums[blockIdx.x] = sdata[255];
}
__global__ void scan2_kernel(int* blockSums, int nb) {
    if (threadIdx.x == 0 && blockIdx.x == 0) {
        int s = 0;
        for (int i = 0; i < nb; ++i) { int v = blockSums[i]; blockSums[i] = s; s += v; }
    }
}
__global__ void scan3_kernel(int* __restrict__ row_ptr, int* __restrict__ cursor,
                             const int* __restrict__ blockSums, int n, int e) {
    int i = blockIdx.x * blockDim.x + threadIdx.x;
    if (i < n) {
        int v = row_ptr[i] + blockSums[i >> 11];
        row_ptr[i] = v;
        cursor[i] = v;
    }
    if (i == 0) row_ptr[n] = e;
}
__global__ void fill_csr_kernel(const int* __restrict__ src, const int* __restrict__ dst,
                                const float* __restrict__ dinv, int* cursor,
                                int2* __restrict__ pairs, int e) {
    int i = blockIdx.x * blockDim.x + threadIdx.x;
    if (i < e) {
        int s = src[i], d = dst[i];
        int pos = atomicAdd(&cursor[d], 1);
        float nv = dinv[s] * dinv[d];
        pairs[pos] = make_int2(s, __float_as_int(nv));
    }
}

// ---------------------------------------------------------------------------
// APPNP step, TWO-KERNEL split (key change vs r8: separate kernels so the
// 1.6 MB hi table owns its L2 without lo-gather pollution):
//  - lo kernel: h_lo[N][32] bf16, 64B-aligned rows -> EXACTLY 1 line/edge.
//    4 threads/node (f=0..3), 64 nodes / 256-thread block, x8 unroll.
//  - hi kernel: h_hi[N][8] bf16 (1.6 MB, L2-resident per XCD).
//    1 thread/node, 256/block, x8 unroll.
// fp32 accumulate; teleport reads fp32 h0f. Numerics == r8 (passed).
// ---------------------------------------------------------------------------
__global__ __launch_bounds__(256)
void prop_lo_kernel(const short* __restrict__ hin_lo, const float* __restrict__ h0f,
                    const int* __restrict__ rowp, const int2* __restrict__ pairs,
                    const float* __restrict__ dinv2,
                    short* __restrict__ hout_lo, float* __restrict__ outF, int n)
{
    const int t = threadIdx.x;
    const int vl = t >> 2;
    const int f = t & 3;                   // feature chunk [f*8, f*8+8)
    const int v = blockIdx.x * 64 + vl;
    if (v >= n) return;

    float acc[8];
    {
        const float dv = dinv2[v];
        s16x8 s = *(const s16x8*)(hin_lo + (size_t)v * 32 + f * 8);
        #pragma unroll
        for (int j = 0; j < 8; ++j) acc[j] = dv * bf2f(s[j]);
    }

    int e = rowp[v];
    const int e1 = rowp[v + 1];

    for (; e + 8 <= e1; e += 8) {
        int2 p0 = pairs[e],     p1 = pairs[e + 1], p2 = pairs[e + 2], p3 = pairs[e + 3];
        int2 p4 = pairs[e + 4], p5 = pairs[e + 5], p6 = pairs[e + 6], p7 = pairs[e + 7];
        s16x8 g0 = *(const s16x8*)(hin_lo + (size_t)p0.x * 32 + f * 8);
        s16x8 g1 = *(const s16x8*)(hin_lo + (size_t)p1.x * 32 + f * 8);
        s16x8 g2 = *(const s16x8*)(hin_lo + (size_t)p2.x * 32 + f * 8);
        s16x8 g3 = *(const s16x8*)(hin_lo + (size_t)p3.x * 32 + f * 8);
        s16x8 g4 = *(const s16x8*)(hin_lo + (size_t)p4.x * 32 + f * 8);
        s16x8 g5 = *(const s16x8*)(hin_lo + (size_t)p5.x * 32 + f * 8);
        s16x8 g6 = *(const s16x8*)(hin_lo + (size_t)p6.x * 32 + f * 8);
        s16x8 g7 = *(const s16x8*)(hin_lo + (size_t)p7.x * 32 + f * 8);
        float w0 = __int_as_float(p0.y), w1 = __int_as_float(p1.y);
        float w2 = __int_as_float(p2.y), w3 = __int_as_float(p3.y);
        float w4 = __int_as_float(p4.y), w5 = __int_as_float(p5.y);
        float w6 = __int_as_float(p6.y), w7 = __int_as_float(p7.y);
        #pragma unroll
        for (int j = 0; j < 8; ++j) acc[j] = fmaf(w0, bf2f(g0[j]), acc[j]);
        #pragma unroll
        for (int j = 0; j < 8; ++j) acc[j] = fmaf(w1, bf2f(g1[j]), acc[j]);
        #pragma unroll
        for (int j = 0; j < 8; ++j) acc[j] = fmaf(w2, bf2f(g2[j]), acc[j]);
        #pragma unroll
        for (int j = 0; j < 8; ++j) acc[j] = fmaf(w3, bf2f(g3[j]), acc[j]);
        #pragma unroll
        for (int j = 0; j < 8; ++j) acc[j] = fmaf(w4, bf2f(g4[j]), acc[j]);
        #pragma unroll
        for (int j = 0; j < 8; ++j) acc[j] = fmaf(w5, bf2f(g5[j]), acc[j]);
        #pragma unroll
        for (int j = 0; j < 8; ++j) acc[j] = fmaf(w6, bf2f(g6[j]), acc[j]);
        #pragma unroll
        for (int j = 0; j < 8; ++j) acc[j] = fmaf(w7, bf2f(g7[j]), acc[j]);
    }
    for (; e < e1; ++e) {
        int2 p = pairs[e];
        s16x8 g = *(const s16x8*)(hin_lo + (size_t)p.x * 32 + f * 8);
        float w = __int_as_float(p.y);
        #pragma unroll
        for (int j = 0; j < 8; ++j) acc[j] = fmaf(w, bf2f(g[j]), acc[j]);
    }

    const float* h0p = h0f + (size_t)v * 40 + f * 8;
    float o[8];
    #pragma unroll
    for (int j = 0; j < 8; ++j) o[j] = fmaf(0.9f, acc[j], 0.1f * h0p[j]);

    if (outF) {
        float4* op = (float4*)(outF + (size_t)v * 40 + f * 8);
        op[0] = make_float4(o[0], o[1], o[2], o[3]);
        op[1] = make_float4(o[4], o[5], o[6], o[7]);
    } else {
        s16x8 s;
        #pragma unroll
        for (int j = 0; j < 8; ++j) s[j] = f2bf(o[j]);
        *(s16x8*)(hout_lo + (size_t)v * 32 + f * 8) = s;
    }
}

__global__ __launch_bounds__(256)
void prop_hi_kernel(const short* __restrict__ hin_hi, const float* __restrict__ h0f,
                    const int* __restrict__ rowp, const int2* __restrict__ pairs,
                    const float* __restrict__ dinv2,
                    short* __restrict__ hout_hi, float* __restrict__ outF, int n)
{
    const int v = blockIdx.x * 256 + threadIdx.x;
    if (v >= n) return;

    float acc[8];
    {
        const float dv = dinv2[v];
        s16x8 s = *(const s16x8*)(hin_hi + (size_t)v * 8);
        #pragma unroll
        for (int j = 0; j < 8; ++j) acc[j] = dv * bf2f(s[j]);
    }

    int e = rowp[v];
    const int e1 = rowp[v + 1];

    for (; e + 8 <= e1; e += 8) {
        int2 p0 = pairs[e],     p1 = pairs[e + 1], p2 = pairs[e + 2], p3 = pairs[e + 3];
        int2 p4 = pairs[e + 4], p5 = pairs[e + 5], p6 = pairs[e + 6], p7 = pairs[e + 7];
        s16x8 g0 = *(const s16x8*)(hin_hi + (size_t)p0.x * 8);
        s16x8 g1 = *(const s16x8*)(hin_hi + (size_t)p1.x * 8);
        s16x8 g2 = *(const s16x8*)(hin_hi + (size_t)p2.x * 8);
        s16x8 g3 = *(const s16x8*)(hin_hi + (size_t)p3.x * 8);
        s16x8 g4 = *(const s16x8*)(hin_hi + (size_t)p4.x * 8);
        s16x8 g5 = *(const s16x8*)(hin_hi + (size_t)p5.x * 8);
        s16x8 g6 = *(const s16x8*)(hin_hi + (size_t)p6.x * 8);
        s16x8 g7 = *(const s16x8*)(hin_hi + (size_t)p7.x * 8);
        float w0 = __int_as_float(p0.y), w1 = __int_as_float(p1.y);
        float w2 = __int_as_float(p2.y), w3 = __int_as_float(p3.y);
        float w4 = __int_as_float(p4.y), w5 = __int_as_float(p5.y);
        float w6 = __int_as_float(p6.y), w7 = __int_as_float(p7.y);
        #pragma unroll
        for (int j = 0; j < 8; ++j) acc[j] = fmaf(w0, bf2f(g0[j]), acc[j]);
        #pragma unroll
        for (int j = 0; j < 8; ++j) acc[j] = fmaf(w1, bf2f(g1[j]), acc[j]);
        #pragma unroll
        for (int j = 0; j < 8; ++j) acc[j] = fmaf(w2, bf2f(g2[j]), acc[j]);
        #pragma unroll
        for (int j = 0; j < 8; ++j) acc[j] = fmaf(w3, bf2f(g3[j]), acc[j]);
        #pragma unroll
        for (int j = 0; j < 8; ++j) acc[j] = fmaf(w4, bf2f(g4[j]), acc[j]);
        #pragma unroll
        for (int j = 0; j < 8; ++j) acc[j] = fmaf(w5, bf2f(g5[j]), acc[j]);
        #pragma unroll
        for (int j = 0; j < 8; ++j) acc[j] = fmaf(w6, bf2f(g6[j]), acc[j]);
        #pragma unroll
        for (int j = 0; j < 8; ++j) acc[j] = fmaf(w7, bf2f(g7[j]), acc[j]);
    }
    for (; e < e1; ++e) {
        int2 p = pairs[e];
        s16x8 g = *(const s16x8*)(hin_hi + (size_t)p.x * 8);
        float w = __int_as_float(p.y);
        #pragma unroll
        for (int j = 0; j < 8; ++j) acc[j] = fmaf(w, bf2f(g[j]), acc[j]);
    }

    const float* h0p = h0f + (size_t)v * 40 + 32;
    float o[8];
    #pragma unroll
    for (int j = 0; j < 8; ++j) o[j] = fmaf(0.9f, acc[j], 0.1f * h0p[j]);

    if (outF) {
        float4* op = (float4*)(outF + (size_t)v * 40 + 32);
        op[0] = make_float4(o[0], o[1], o[2], o[3]);
        op[1] = make_float4(o[4], o[5], o[6], o[7]);
    } else {
        s16x8 s;
        #pragma unroll
        for (int j = 0; j < 8; ++j) s[j] = f2bf(o[j]);
        *(s16x8*)(hout_hi + (size_t)v * 8) = s;
    }
}

// ---------------------------------------------------------------------------
extern "C" void kernel_launch(void* const* d_in, const int* in_sizes, int n_in,
                              void* d_out, int out_size, void* d_ws, size_t ws_size,
                              hipStream_t stream) {
    const float* x  = (const float*)d_in[0];
    const int* ei   = (const int*)d_in[1];
    const float* W0 = (const float*)d_in[2];
    const float* b0 = (const float*)d_in[3];
    const float* W1 = (const float*)d_in[4];
    const float* b1 = (const float*)d_in[5];
    const float* W2 = (const float*)d_in[6];
    const float* b2 = (const float*)d_in[7];
    float* out = (float*)d_out;
    char* ws = (char*)d_ws;

    const int* src = ei;
    const int* dst = ei + EE;

    // ---- Workspace layout (round-8 proven scheme), total 151.6 MB ----
    short* xb   = (short*)(ws);                   // [N][500] bf16
    short* h1b  = (short*)(ws + 100000000);       // [N][256] bf16
    short* W0b  = (short*)(ws + 151200000);       // [256][512]
    short* W1b  = (short*)(ws + 151462144);       // [128][256]
    short* W2b  = (short*)(ws + 151527680);       // [128][128] (ends 151,560,448)

    short* h2b  = (short*)(ws);                   // [N][128] bf16 (reuse xb)
    short* h0lo = (short*)(ws + 25600000);        // [N][32] bf16 (64B rows)
    short* h0hi = (short*)(ws + 32000000);        // [N][8]  bf16 (1.6 MB)
    float* h0f  = (float*)(ws + 33600000);        // [N][40] f32
    short* hAlo = (short*)(ws + 49600000);        // [N][32]
    short* hAhi = (short*)(ws + 56000000);        // [N][8]
    short* hBlo = (short*)(ws + 57600000);        // [N][32]
    short* hBhi = (short*)(ws + 64000000);        // [N][8]  (ends 65.6e6)

    int2*  pairs= (int2*) (ws + 100000000);       // [E] (reuse h1b)
    int*   deg  = (int*)  (ws + 112800000);       // [N]
    float* dinv = (float*)(ws + 113200000);       // [N]
    float* dnv2 = (float*)(ws + 113600000);       // [N]
    int*   rowp = (int*)  (ws + 114000000);       // [N+1]
    int*   curs = (int*)  (ws + 114400008);       // [N]
    int*   bsum = (int*)  (ws + 114800008);       // [4096]
    (void)ws_size; (void)in_sizes; (void)n_in; (void)out_size;

    // ---- conversions ----
    convert_x_kernel<<<((NN * 500 / 8) + 255) / 256, 256, 0, stream>>>(x, xb);
    convert_w_kernel<<<(256 * 512 + 255) / 256, 256, 0, stream>>>(W0, W0b, 256, 500, 256, 512);
    convert_w_kernel<<<(128 * 256 + 255) / 256, 256, 0, stream>>>(W1, W1b, 128, 256, 128, 256);
    convert_w_kernel<<<(128 * 128 + 255) / 256, 256, 0, stream>>>(W2, W2b, 40, 128, 128, 128);

    // ---- MLP encoder ----
    const int NBLK = (NN + 127) / 128;  // 782
    mfma_gemm<16, true ><<<dim3(2, NBLK), 256, 0, stream>>>(
        xb, 500, W0b, b0, 256, (void*)h1b, nullptr, 256, 256, NN, nullptr);
    mfma_gemm<8,  true ><<<dim3(1, NBLK), 256, 0, stream>>>(
        h1b, 256, W1b, b1, 128, (void*)h2b, nullptr, 128, 128, NN, nullptr);
    mfma_gemm<4,  true ><<<dim3(1, NBLK), 256, 0, stream>>>(
        h2b, 128, W2b, b2, 40, (void*)h0lo, h0hi, 40, 40, NN, h0f);

    // ---- graph build (after GEMM1: h1b region is dead) ----
    {
        int nb_n = (NN + 255) / 256;
        int nb_e = (EE + 255) / 256;
        deg_init_kernel<<<nb_n, 256, 0, stream>>>(deg, NN);
        deg_count_kernel<<<nb_e, 256, 0, stream>>>(dst, deg, EE);
        dinv_kernel<<<nb_n, 256, 0, stream>>>(deg, dinv, dnv2, NN);
        int nb_scan = (NN + 2047) / 2048;
        scan1_kernel<<<nb_scan, 256, 0, stream>>>(deg, rowp, bsum, NN);
        scan2_kernel<<<1, 64, 0, stream>>>(bsum, nb_scan);
        scan3_kernel<<<nb_n, 256, 0, stream>>>(rowp, curs, bsum, NN, EE);
        fill_csr_kernel<<<nb_e, 256, 0, stream>>>(src, dst, dinv, curs, pairs, EE);
    }

    // ---- APPNP propagation: lo (64B rows, 1 line/edge) + hi (L2-resident) ----
    {
        dim3 gLo((NN + 63) / 64);    // 1563 blocks x 256 thr (4 thr/node)
        dim3 gHi((NN + 255) / 256);  // 391 blocks x 256 thr (1 thr/node)
        const short* hlo = h0lo;
        const short* hhi = h0hi;
        for (int it = 0; it < KITER; ++it) {
            short* olo = (it & 1) ? hBlo : hAlo;
            short* ohi = (it & 1) ? hBhi : hAhi;
            float* fin = (it == KITER - 1) ? out : nullptr;
            prop_lo_kernel<<<gLo, 256, 0, stream>>>(
                hlo, h0f, rowp, pairs, dnv2, olo, fin, NN);
            prop_hi_kernel<<<gHi, 256, 0, stream>>>(
                hhi, h0f, rowp, pairs, dnv2, ohi, fin, NN);
            hlo = olo; hhi = ohi;
        }
    }
}

// Round 11
// 755.750 us; speedup vs baseline: 1.1166x; 1.0899x over previous
//
#include <hip/hip_runtime.h>

#define NN 100000
#define EE 1600000
#define KITER 10

typedef __attribute__((ext_vector_type(8))) short s16x8;
typedef __attribute__((ext_vector_type(4))) float f32x4;

__device__ __forceinline__ short f2bf(float f) {
    union { float f; unsigned u; } v; v.f = f;
    unsigned r = v.u + 0x7FFFu + ((v.u >> 16) & 1u);   // RNE
    return (short)(r >> 16);
}
__device__ __forceinline__ float bf2f(short s) {
    return __uint_as_float((unsigned)(unsigned short)s << 16);
}

__device__ __forceinline__ void gload_lds16(const void* g, void* l) {
    __builtin_amdgcn_global_load_lds(
        (const __attribute__((address_space(1))) void*)g,
        (__attribute__((address_space(3))) void*)l, 16, 0, 0);
}

// ---------------------------------------------------------------------------
// bf16 MFMA GEMM: C = relu(A @ W^T + bias). Tile 128x128, 4 waves, 16x16x32.
// PROVEN round-7 kernel (756 us, absmax 0.0078125), unchanged.
// ---------------------------------------------------------------------------
template<int KSTEPS, bool OUT_BF16>
__global__ __launch_bounds__(256)
void mfma_gemm(const short* __restrict__ A, int lda, const short* __restrict__ B,
               const float* __restrict__ bias, int nbias,
               void* __restrict__ Cout, int ldc, int ncols_store, int nrows,
               float* __restrict__ C2)
{
    __shared__ short ldsA[128 * 32];
    __shared__ short ldsB[128 * 32];
    const int t    = threadIdx.x;
    const int lane = t & 63;
    const int wid  = t >> 6;
    const int rowBase = blockIdx.y * 128;
    const int colBase = blockIdx.x * 128;
    const int wrow = (wid >> 1) * 64;
    const int wcol = (wid & 1) * 64;

    const int q  = t & 3;    // 8-elem (16B) chunk within 32-wide k tile
    const int rl = t >> 2;   // 0..63

    f32x4 acc[4][4] = {};
    const int KPB = KSTEPS * 32;   // B row stride (padded)

    for (int ks = 0; ks < KSTEPS; ++ks) {
        const int k0 = ks * 32;

        #pragma unroll
        for (int i = 0; i < 2; ++i) {
            const short* srcB = B + (size_t)(colBase + rl + i * 64) * KPB + k0 + q * 8;
            gload_lds16(srcB, &ldsB[wid * 512 + i * 2048]);
        }
        #pragma unroll
        for (int i = 0; i < 2; ++i) {
            int grow = rowBase + rl + i * 64; if (grow > NN - 1) grow = NN - 1;
            const short* srcA = A + (size_t)grow * lda + k0 + q * 8;
            gload_lds16(srcA, &ldsA[wid * 512 + i * 2048]);
        }

        __syncthreads();

        {
            const int kb = lane >> 4;
            const int l16 = lane & 15;
            s16x8 a[4], b[4];
            #pragma unroll
            for (int m = 0; m < 4; ++m)
                a[m] = *(const s16x8*)&ldsA[(wrow + m * 16 + l16) * 32 + kb * 8];
            #pragma unroll
            for (int n = 0; n < 4; ++n)
                b[n] = *(const s16x8*)&ldsB[(wcol + n * 16 + l16) * 32 + kb * 8];
            #pragma unroll
            for (int m = 0; m < 4; ++m)
                #pragma unroll
                for (int n = 0; n < 4; ++n)
                    acc[m][n] = __builtin_amdgcn_mfma_f32_16x16x32_bf16(
                        a[m], b[n], acc[m][n], 0, 0, 0);
        }

        __syncthreads();
    }

    const int crow0 = (lane >> 4) * 4;
    const int ccol  = lane & 15;
    #pragma unroll
    for (int n = 0; n < 4; ++n) {
        int col = colBase + wcol + n * 16 + ccol;
        float bv = (col < nbias) ? bias[col] : 0.f;
        #pragma unroll
        for (int m = 0; m < 4; ++m) {
            #pragma unroll
            for (int j = 0; j < 4; ++j) {
                int row = rowBase + wrow + m * 16 + crow0 + j;
                if (row >= nrows) continue;
                float v = acc[m][n][j] + bv;
                v = fmaxf(v, 0.f);
                if (col < ncols_store) {
                    if (OUT_BF16)
                        ((short*)Cout)[(size_t)row * ldc + col] = f2bf(v);
                    else
                        ((float*)Cout)[(size_t)row * ldc + col] = v;
                    if (C2) C2[(size_t)row * ldc + col] = v;
                }
            }
        }
    }
}

// ---------------------------------------------------------------------------
// x fp32 [N][500] -> bf16 [N][500] contiguous, 8 elems/thread
// ---------------------------------------------------------------------------
__global__ void convert_x_kernel(const float* __restrict__ in, short* __restrict__ out) {
    int idx = blockIdx.x * blockDim.x + threadIdx.x;
    if (idx >= (NN * 500) / 8) return;
    const float4* in4 = (const float4*)in;
    float4 a = in4[(size_t)idx * 2];
    float4 b = in4[(size_t)idx * 2 + 1];
    s16x8 s;
    s[0]=f2bf(a.x); s[1]=f2bf(a.y); s[2]=f2bf(a.z); s[3]=f2bf(a.w);
    s[4]=f2bf(b.x); s[5]=f2bf(b.y); s[6]=f2bf(b.z); s[7]=f2bf(b.w);
    *(s16x8*)&out[(size_t)idx * 8] = s;
}

__global__ void convert_w_kernel(const float* __restrict__ in, short* __restrict__ out,
                                 int R, int C, int Rp, int Cp) {
    int idx = blockIdx.x * blockDim.x + threadIdx.x;
    if (idx >= Rp * Cp) return;
    int r = idx / Cp, c = idx - r * Cp;
    float v = (r < R && c < C) ? in[r * C + c] : 0.f;
    out[idx] = f2bf(v);
}

// ---------------------------------------------------------------------------
// Graph build: CSR-by-dst with packed (src, norm) pairs
// ---------------------------------------------------------------------------
__global__ void deg_init_kernel(int* deg, int n) {
    int i = blockIdx.x * blockDim.x + threadIdx.x;
    if (i < n) deg[i] = 1;
}
__global__ void deg_count_kernel(const int* __restrict__ dst, int* deg, int e) {
    int i = blockIdx.x * blockDim.x + threadIdx.x;
    if (i < e) atomicAdd(&deg[dst[i]], 1);
}
__global__ void dinv_kernel(const int* __restrict__ deg, float* __restrict__ dinv,
                            float* __restrict__ dinv2, int n) {
    int i = blockIdx.x * blockDim.x + threadIdx.x;
    if (i < n) {
        float d = (float)deg[i];
        dinv[i] = rsqrtf(d);
        dinv2[i] = 1.0f / d;
    }
}
__global__ __launch_bounds__(256)
void scan1_kernel(const int* __restrict__ deg, int* __restrict__ row_ptr,
                  int* __restrict__ blockSums, int n) {
    __shared__ int sdata[256];
    const int base = blockIdx.x * 2048;
    const int t = threadIdx.x;
    int local[8];
    int s = 0;
    #pragma unroll
    for (int i = 0; i < 8; ++i) {
        int idx = base + t * 8 + i;
        int c = (idx < n) ? (deg[idx] - 1) : 0;
        local[i] = s;
        s += c;
    }
    sdata[t] = s;
    __syncthreads();
    for (int off = 1; off < 256; off <<= 1) {
        int v = (t >= off) ? sdata[t - off] : 0;
        __syncthreads();
        sdata[t] += v;
        __syncthreads();
    }
    int excl = (t == 0) ? 0 : sdata[t - 1];
    #pragma unroll
    for (int i = 0; i < 8; ++i) {
        int idx = base + t * 8 + i;
        if (idx < n) row_ptr[idx] = excl + local[i];
    }
    if (t == 255) blockSums[blockIdx.x] = sdata[255];
}
__global__ void scan2_kernel(int* blockSums, int nb) {
    if (threadIdx.x == 0 && blockIdx.x == 0) {
        int s = 0;
        for (int i = 0; i < nb; ++i) { int v = blockSums[i]; blockSums[i] = s; s += v; }
    }
}
__global__ void scan3_kernel(int* __restrict__ row_ptr, int* __restrict__ cursor,
                             const int* __restrict__ blockSums, int n, int e) {
    int i = blockIdx.x * blockDim.x + threadIdx.x;
    if (i < n) {
        int v = row_ptr[i] + blockSums[i >> 11];
        row_ptr[i] = v;
        cursor[i] = v;
    }
    if (i == 0) row_ptr[n] = e;
}
__global__ void fill_csr_kernel(const int* __restrict__ src, const int* __restrict__ dst,
                                const float* __restrict__ dinv, int* cursor,
                                int2* __restrict__ pairs, int e) {
    int i = blockIdx.x * blockDim.x + threadIdx.x;
    if (i < e) {
        int s = src[i], d = dst[i];
        int pos = atomicAdd(&cursor[d], 1);
        float nv = dinv[s] * dinv[d];
        pairs[pos] = make_int2(s, __float_as_int(nv));
    }
}

// ---------------------------------------------------------------------------
// APPNP step, bf16 state (PROVEN round-7 kernel, 48 us/iter): h stored
// [N][40] bf16 (80B rows = 2 cache lines). 5 threads/node x 16B, 64 nodes
// per 320-thread block; fp32 accumulate; teleport reads fp32 h0f; x8 unroll.
// ---------------------------------------------------------------------------
__global__ __launch_bounds__(320)
void prop_bf16_kernel(const short* __restrict__ hin, const float* __restrict__ h0f,
                      const int* __restrict__ rowp, const int2* __restrict__ pairs,
                      const float* __restrict__ dinv2,
                      short* __restrict__ hout, float* __restrict__ outF, int n)
{
    const int t = threadIdx.x;
    const int vl = t / 5;
    const int f = t - vl * 5;              // 0..4 -> features [f*8, f*8+8)
    const int v = blockIdx.x * 64 + vl;
    if (v >= n) return;

    float acc[8];
    {
        const float dv = dinv2[v];
        s16x8 s = *(const s16x8*)(hin + (size_t)v * 40 + f * 8);
        #pragma unroll
        for (int j = 0; j < 8; ++j) acc[j] = dv * bf2f(s[j]);
    }

    int e = rowp[v];
    const int e1 = rowp[v + 1];

    for (; e + 8 <= e1; e += 8) {
        int2 p0 = pairs[e],     p1 = pairs[e + 1], p2 = pairs[e + 2], p3 = pairs[e + 3];
        int2 p4 = pairs[e + 4], p5 = pairs[e + 5], p6 = pairs[e + 6], p7 = pairs[e + 7];
        s16x8 g0 = *(const s16x8*)(hin + (size_t)p0.x * 40 + f * 8);
        s16x8 g1 = *(const s16x8*)(hin + (size_t)p1.x * 40 + f * 8);
        s16x8 g2 = *(const s16x8*)(hin + (size_t)p2.x * 40 + f * 8);
        s16x8 g3 = *(const s16x8*)(hin + (size_t)p3.x * 40 + f * 8);
        s16x8 g4 = *(const s16x8*)(hin + (size_t)p4.x * 40 + f * 8);
        s16x8 g5 = *(const s16x8*)(hin + (size_t)p5.x * 40 + f * 8);
        s16x8 g6 = *(const s16x8*)(hin + (size_t)p6.x * 40 + f * 8);
        s16x8 g7 = *(const s16x8*)(hin + (size_t)p7.x * 40 + f * 8);
        float w0 = __int_as_float(p0.y), w1 = __int_as_float(p1.y);
        float w2 = __int_as_float(p2.y), w3 = __int_as_float(p3.y);
        float w4 = __int_as_float(p4.y), w5 = __int_as_float(p5.y);
        float w6 = __int_as_float(p6.y), w7 = __int_as_float(p7.y);
        #pragma unroll
        for (int j = 0; j < 8; ++j) acc[j] = fmaf(w0, bf2f(g0[j]), acc[j]);
        #pragma unroll
        for (int j = 0; j < 8; ++j) acc[j] = fmaf(w1, bf2f(g1[j]), acc[j]);
        #pragma unroll
        for (int j = 0; j < 8; ++j) acc[j] = fmaf(w2, bf2f(g2[j]), acc[j]);
        #pragma unroll
        for (int j = 0; j < 8; ++j) acc[j] = fmaf(w3, bf2f(g3[j]), acc[j]);
        #pragma unroll
        for (int j = 0; j < 8; ++j) acc[j] = fmaf(w4, bf2f(g4[j]), acc[j]);
        #pragma unroll
        for (int j = 0; j < 8; ++j) acc[j] = fmaf(w5, bf2f(g5[j]), acc[j]);
        #pragma unroll
        for (int j = 0; j < 8; ++j) acc[j] = fmaf(w6, bf2f(g6[j]), acc[j]);
        #pragma unroll
        for (int j = 0; j < 8; ++j) acc[j] = fmaf(w7, bf2f(g7[j]), acc[j]);
    }
    for (; e < e1; ++e) {
        int2 p = pairs[e];
        s16x8 g = *(const s16x8*)(hin + (size_t)p.x * 40 + f * 8);
        float w = __int_as_float(p.y);
        #pragma unroll
        for (int j = 0; j < 8; ++j) acc[j] = fmaf(w, bf2f(g[j]), acc[j]);
    }

    const float* h0p = h0f + (size_t)v * 40 + f * 8;
    float o[8];
    #pragma unroll
    for (int j = 0; j < 8; ++j) o[j] = fmaf(0.9f, acc[j], 0.1f * h0p[j]);

    if (outF) {
        float4* op = (float4*)(outF + (size_t)v * 40 + f * 8);
        op[0] = make_float4(o[0], o[1], o[2], o[3]);
        op[1] = make_float4(o[4], o[5], o[6], o[7]);
    } else {
        s16x8 s;
        #pragma unroll
        for (int j = 0; j < 8; ++j) s[j] = f2bf(o[j]);
        *(s16x8*)(hout + (size_t)v * 40 + f * 8) = s;
    }
}

// ---------------------------------------------------------------------------
extern "C" void kernel_launch(void* const* d_in, const int* in_sizes, int n_in,
                              void* d_out, int out_size, void* d_ws, size_t ws_size,
                              hipStream_t stream) {
    const float* x  = (const float*)d_in[0];
    const int* ei   = (const int*)d_in[1];
    const float* W0 = (const float*)d_in[2];
    const float* b0 = (const float*)d_in[3];
    const float* W1 = (const float*)d_in[4];
    const float* b1 = (const float*)d_in[5];
    const float* W2 = (const float*)d_in[6];
    const float* b2 = (const float*)d_in[7];
    float* out = (float*)d_out;
    char* ws = (char*)d_ws;

    const int* src = ei;
    const int* dst = ei + EE;

    // ---- Workspace layout (round-7 proven), total 151.6 MB ----
    short* xb   = (short*)(ws);                   // [N][500] bf16
    short* h1b  = (short*)(ws + 100000000);       // [N][256] bf16
    short* W0b  = (short*)(ws + 151200000);       // [256][512]
    short* W1b  = (short*)(ws + 151462144);       // [128][256]
    short* W2b  = (short*)(ws + 151527680);       // [128][128] (ends 151,560,448)

    short* h2b  = (short*)(ws);                   // [N][128] bf16 (reuse xb)
    short* h0b  = (short*)(ws + 25600000);        // [N][40] bf16  ->  33.6e6
    float* h0f  = (float*)(ws + 33600000);        // [N][40] f32   ->  49.6e6
    short* hA   = (short*)(ws + 49600000);        // [N][40] bf16  ->  57.6e6
    short* hB   = (short*)(ws + 57600000);        // [N][40] bf16  ->  65.6e6

    int2*  pairs= (int2*) (ws + 100000000);       // [E] (reuse h1b)
    int*   deg  = (int*)  (ws + 112800000);       // [N]
    float* dinv = (float*)(ws + 113200000);       // [N]
    float* dnv2 = (float*)(ws + 113600000);       // [N]
    int*   rowp = (int*)  (ws + 114000000);       // [N+1]
    int*   curs = (int*)  (ws + 114400008);       // [N]
    int*   bsum = (int*)  (ws + 114800008);       // [4096]
    (void)ws_size; (void)in_sizes; (void)n_in; (void)out_size;

    // ---- conversions ----
    convert_x_kernel<<<((NN * 500 / 8) + 255) / 256, 256, 0, stream>>>(x, xb);
    convert_w_kernel<<<(256 * 512 + 255) / 256, 256, 0, stream>>>(W0, W0b, 256, 500, 256, 512);
    convert_w_kernel<<<(128 * 256 + 255) / 256, 256, 0, stream>>>(W1, W1b, 128, 256, 128, 256);
    convert_w_kernel<<<(128 * 128 + 255) / 256, 256, 0, stream>>>(W2, W2b, 40, 128, 128, 128);

    // ---- MLP encoder ----
    const int NBLK = (NN + 127) / 128;  // 782
    mfma_gemm<16, true ><<<dim3(2, NBLK), 256, 0, stream>>>(
        xb, 500, W0b, b0, 256, (void*)h1b, 256, 256, NN, nullptr);
    mfma_gemm<8,  true ><<<dim3(1, NBLK), 256, 0, stream>>>(
        h1b, 256, W1b, b1, 128, (void*)h2b, 128, 128, NN, nullptr);
    mfma_gemm<4,  true ><<<dim3(1, NBLK), 256, 0, stream>>>(
        h2b, 128, W2b, b2, 40, (void*)h0b, 40, 40, NN, h0f);  // bf16 + fp32 h0

    // ---- graph build (after GEMM1: h1b region is dead) ----
    {
        int nb_n = (NN + 255) / 256;
        int nb_e = (EE + 255) / 256;
        deg_init_kernel<<<nb_n, 256, 0, stream>>>(deg, NN);
        deg_count_kernel<<<nb_e, 256, 0, stream>>>(dst, deg, EE);
        dinv_kernel<<<nb_n, 256, 0, stream>>>(deg, dinv, dnv2, NN);
        int nb_scan = (NN + 2047) / 2048;
        scan1_kernel<<<nb_scan, 256, 0, stream>>>(deg, rowp, bsum, NN);
        scan2_kernel<<<1, 64, 0, stream>>>(bsum, nb_scan);
        scan3_kernel<<<nb_n, 256, 0, stream>>>(rowp, curs, bsum, NN, EE);
        fill_csr_kernel<<<nb_e, 256, 0, stream>>>(src, dst, dinv, curs, pairs, EE);
    }

    // ---- APPNP propagation (bf16 state) ----
    {
        dim3 blk(320);
        dim3 grd((NN + 63) / 64);  // 1563
        const short* hin = h0b;
        for (int it = 0; it < KITER; ++it) {
            short* hout = (it & 1) ? hB : hA;
            float* fin  = (it == KITER - 1) ? out : nullptr;
            prop_bf16_kernel<<<grd, blk, 0, stream>>>(
                hin, h0f, rowp, pairs, dnv2, hout, fin, NN);
            hin = hout;
        }
    }
}